// Round 7
// baseline (106.228 us; speedup 1.0000x reference)
//
#include <hip/hip_runtime.h>
#include <math.h>

#define F_IN  128
#define F_OUT 256
#define GBITS 5            // 32 nodes per group
#define G_MAX 380          // LDS array bound (G = ceil(n/32) = 375 for n=12000)
#define WPR   376          // padded words per LDS bitmap row (>= ceil(n/32))
#define NBLK  256          // edge-pass blocks (k_count / k_scatter must match)

// ---------------------------------------------------------------------------
// P1: per-block group histogram of incidences. Edge (a,b) contributes an
// incidence to group(a) and group(b). LDS atomics only.
// ---------------------------------------------------------------------------
__global__ __launch_bounds__(256)
void k_count(const int* __restrict__ ei, int E, int G,
             int* __restrict__ counts /* [NBLK][G] */) {
    __shared__ int hist[G_MAX];
    int b = blockIdx.x, t = threadIdx.x;
    for (int g = t; g < G; g += 256) hist[g] = 0;
    __syncthreads();
    int C = (E + (int)gridDim.x - 1) / (int)gridDim.x;
    int e0 = b * C, e1 = min(E, e0 + C);
    for (int e = e0 + t; e < e1; e += 256) {
        int a = ei[e], c = ei[E + e];
        atomicAdd(&hist[a >> GBITS], 1);
        atomicAdd(&hist[c >> GBITS], 1);
    }
    __syncthreads();
    for (int g = t; g < G; g += 256)
        counts[(size_t)b * G + g] = hist[g];
}

// ---------------------------------------------------------------------------
// P2: one block. off[b][g] = exclusive prefix of counts over b (within group);
// base[g] = exclusive prefix of group totals; endg[g] = base+total.
// Reads/writes coalesced across the g-threads at each b-iteration.
// ---------------------------------------------------------------------------
__global__ __launch_bounds__(512)
void k_prefix(const int* __restrict__ counts, int G, int B,
              int* __restrict__ off, int* __restrict__ base,
              int* __restrict__ endg) {
    __shared__ int tg[G_MAX];
    int t = threadIdx.x;
    int run = 0;
    if (t < G) {
        for (int b = 0; b < B; ++b) {
            int c = counts[(size_t)b * G + t];
            off[(size_t)b * G + t] = run;
            run += c;
        }
        tg[t] = run;                       // group total
    }
    __syncthreads();
    if (t == 0) {
        int acc = 0;
        for (int g = 0; g < G; ++g) { int c = tg[g]; tg[g] = acc; acc += c; }
    }
    __syncthreads();
    if (t < G) {
        base[t] = tg[t];
        endg[t] = tg[t] + run;
    }
}

// ---------------------------------------------------------------------------
// P3: scatter incidences into group buckets. Cursors live in LDS (fast
// atomics); bucket content per group is a deterministic multiset (order
// irrelevant downstream). pack = (node&31)<<16 | other.
// ---------------------------------------------------------------------------
__global__ __launch_bounds__(256)
void k_scatter(const int* __restrict__ ei, int E, int G,
               const int* __restrict__ off, const int* __restrict__ base,
               unsigned* __restrict__ bucket) {
    __shared__ int cur[G_MAX];
    int b = blockIdx.x, t = threadIdx.x;
    for (int g = t; g < G; g += 256)
        cur[g] = off[(size_t)b * G + g] + base[g];
    __syncthreads();
    int C = (E + (int)gridDim.x - 1) / (int)gridDim.x;
    int e0 = b * C, e1 = min(E, e0 + C);
    for (int e = e0 + t; e < e1; e += 256) {
        int a = ei[e], c = ei[E + e];
        int s1 = atomicAdd(&cur[a >> GBITS], 1);
        bucket[s1] = ((unsigned)(a & 31) << 16) | (unsigned)c;
        int s2 = atomicAdd(&cur[c >> GBITS], 1);
        bucket[s2] = ((unsigned)(c & 31) << 16) | (unsigned)a;
    }
}

// ---------------------------------------------------------------------------
// P4 (fused): per group of 32 nodes — LDS bitmap dedup -> popcount -> dinv,
// then weighted colsum of those 32 x-rows -> partial. All atomics in LDS.
// ---------------------------------------------------------------------------
__global__ __launch_bounds__(256)
void k_dedup_colsum(const unsigned* __restrict__ bucket,
                    const int* __restrict__ base, const int* __restrict__ endg,
                    const float4* __restrict__ x4,
                    float* __restrict__ dinv, float4* __restrict__ partial4,
                    int n) {
    __shared__ unsigned bm[32 * WPR];     // 48128 B
    __shared__ float dloc[32];
    __shared__ float4 red[8][32];
    int g = blockIdx.x, t = threadIdx.x;

    for (int i = t; i < 32 * WPR; i += 256) bm[i] = 0;
    __syncthreads();

    int i0 = base[g], i1 = endg[g];
    for (int i = i0 + t; i < i1; i += 256) {
        unsigned w = bucket[i];
        unsigned lrow = w >> 16, col = w & 0xFFFFu;
        atomicOr(&bm[lrow * WPR + (col >> 5)], 1u << (col & 31));
    }
    __syncthreads();

    // popcount: 4 waves, 8 rows each
    int wave = t >> 6, lane = t & 63;
    int words = (n + 31) >> 5;            // 375
    for (int lrow = wave; lrow < 32; lrow += 4) {
        int node = g * 32 + lrow;
        int cnt = 0;
        for (int w = lane; w < words; w += 64)
            cnt += __popc(bm[lrow * WPR + w]);
        #pragma unroll
        for (int o = 32; o > 0; o >>= 1)
            cnt += __shfl_down(cnt, o, 64);
        if (lane == 0) {
            float dv = 1.0f / sqrtf((float)cnt);   // deg==0 -> inf, matches ref
            dloc[lrow] = dv;
            if (node < n) dinv[node] = dv;
        }
    }
    __syncthreads();

    // weighted colsum for this block's 32 rows (fixed order => deterministic)
    int c4 = t & 31, ro = t >> 5;         // ro 0..7
    float4 acc = make_float4(0.f, 0.f, 0.f, 0.f);
    for (int lrow = ro; lrow < 32; lrow += 8) {
        int node = g * 32 + lrow;
        if (node >= n) break;
        float dv = dloc[lrow];
        float4 v = x4[(size_t)node * (F_IN / 4) + c4];
        acc.x += dv * v.x; acc.y += dv * v.y;
        acc.z += dv * v.z; acc.w += dv * v.w;
    }
    red[ro][c4] = acc;
    __syncthreads();
    if (ro == 0) {
        float4 s = red[0][c4];
        #pragma unroll
        for (int k = 1; k < 8; ++k) {
            float4 v = red[k][c4];
            s.x += v.x; s.y += v.y; s.z += v.z; s.w += v.w;
        }
        partial4[(size_t)g * (F_IN / 4) + c4] = s;
    }
}

// ---------------------------------------------------------------------------
// Reduce partials -> s[128], then agg[f] = sum_k s[k]*W[k,f] (4-way k-split).
// ---------------------------------------------------------------------------
__global__ __launch_bounds__(1024)
void k_reduce_agg(const float4* __restrict__ partial4, int nparts,
                  const float* __restrict__ W, float* __restrict__ agg) {
    __shared__ float4 lds[32][32];
    __shared__ float s[F_IN];
    __shared__ float aggLds[4][F_OUT];
    int t = threadIdx.x;
    int c4 = t & 31;
    int g  = t >> 5;
    {
        float4 acc = make_float4(0.f, 0.f, 0.f, 0.f);
        for (int b = g; b < nparts; b += 32) {
            float4 v = partial4[(size_t)b * (F_IN / 4) + c4];
            acc.x += v.x; acc.y += v.y; acc.z += v.z; acc.w += v.w;
        }
        lds[g][c4] = acc;
    }
    __syncthreads();
    for (int st = 16; st > 0; st >>= 1) {
        if (g < st) {
            float4 o = lds[g + st][c4];
            float4 v = lds[g][c4];
            v.x += o.x; v.y += o.y; v.z += o.z; v.w += o.w;
            lds[g][c4] = v;
        }
        __syncthreads();
    }
    if (g == 0) {
        float4 v = lds[0][c4];
        s[c4 * 4 + 0] = v.x; s[c4 * 4 + 1] = v.y;
        s[c4 * 4 + 2] = v.z; s[c4 * 4 + 3] = v.w;
    }
    __syncthreads();
    {
        int f  = t & 255;
        int kg = t >> 8;
        float acc = 0.f;
        #pragma unroll 8
        for (int k = kg * 32; k < kg * 32 + 32; ++k)
            acc += s[k] * W[(size_t)k * F_OUT + f];
        aggLds[kg][f] = acc;
    }
    __syncthreads();
    if (t < F_OUT)
        agg[t] = aggLds[0][t] + aggLds[1][t] + aggLds[2][t] + aggLds[3][t];
}

// ---------------------------------------------------------------------------
// out[n,f] = dinv[n]*agg[f] + bias[f], float4-vectorized.
// ---------------------------------------------------------------------------
__global__ void k_outer(const float* __restrict__ dinv,
                        const float* __restrict__ agg,
                        const float* __restrict__ bias,
                        float4* __restrict__ out4, int n) {
    int i = blockIdx.x * blockDim.x + threadIdx.x;
    const int per_row = F_OUT / 4;
    int total = n * per_row;
    if (i >= total) return;
    int node = i >> 6;
    int f4   = i & 63;
    float d = dinv[node];
    float4 a  = ((const float4*)agg)[f4];
    float4 bb = ((const float4*)bias)[f4];
    float4 o;
    o.x = fmaf(d, a.x, bb.x);
    o.y = fmaf(d, a.y, bb.y);
    o.z = fmaf(d, a.z, bb.z);
    o.w = fmaf(d, a.w, bb.w);
    out4[i] = o;
}

// ---------------------------------------------------------------------------
// Fallback path (only if n too large for LDS bitmap or ws too small):
// global-bitmap zero / atomicOr / popcount (round-4 structure).
// ---------------------------------------------------------------------------
__global__ __launch_bounds__(256)
void k_zero_simple(float4* __restrict__ p, size_t n4) {
    size_t i = (size_t)blockIdx.x * blockDim.x + threadIdx.x;
    size_t stride = (size_t)gridDim.x * blockDim.x;
    float4 z = make_float4(0.f, 0.f, 0.f, 0.f);
    for (; i < n4; i += stride) p[i] = z;
}
__global__ void k_set_bits_simple(const int* __restrict__ ei, int E,
                                  unsigned* __restrict__ bm, int r0, int r1,
                                  int row_words) {
    int e = blockIdx.x * blockDim.x + threadIdx.x;
    if (e >= E) return;
    int a = ei[e];
    int b = ei[E + e];
    if (a >= r0 && a < r1)
        atomicOr(&bm[(size_t)(a - r0) * row_words + (b >> 5)], 1u << (b & 31));
    if (b >= r0 && b < r1)
        atomicOr(&bm[(size_t)(b - r0) * row_words + (a >> 5)], 1u << (a & 31));
}
__global__ __launch_bounds__(256)
void k_degree_simple(const unsigned* __restrict__ bm, float* __restrict__ dinv,
                     int r0, int rows, int row_words) {
    int wave = threadIdx.x >> 6;
    int lane = threadIdx.x & 63;
    int row  = blockIdx.x * 4 + wave;
    if (row >= rows) return;
    const unsigned* p = bm + (size_t)row * row_words;
    int cnt = 0;
    for (int w = lane; w < row_words; w += 64)
        cnt += __popc(p[w]);
    #pragma unroll
    for (int off = 32; off > 0; off >>= 1)
        cnt += __shfl_down(cnt, off, 64);
    if (lane == 0)
        dinv[r0 + row] = 1.0f / sqrtf((float)cnt);
}
__global__ __launch_bounds__(256)
void k_colsum_simple(const float4* __restrict__ x4, const float* __restrict__ dinv,
                     float4* __restrict__ partial4, int n) {
    __shared__ float4 lds[8][32];
    int t = threadIdx.x;
    int c4 = t & 31;
    int ro = t >> 5;
    int rows_per = (n + (int)gridDim.x - 1) / (int)gridDim.x;
    int rbeg = blockIdx.x * rows_per;
    int rend = rbeg + rows_per; if (rend > n) rend = n;
    float4 acc = make_float4(0.f, 0.f, 0.f, 0.f);
    for (int r = rbeg + ro; r < rend; r += 8) {
        float dv = dinv[r];
        float4 v = x4[(size_t)r * (F_IN / 4) + c4];
        acc.x += dv * v.x; acc.y += dv * v.y;
        acc.z += dv * v.z; acc.w += dv * v.w;
    }
    lds[ro][c4] = acc;
    __syncthreads();
    if (ro == 0) {
        float4 s = lds[0][c4];
        #pragma unroll
        for (int g = 1; g < 8; ++g) {
            float4 v = lds[g][c4];
            s.x += v.x; s.y += v.y; s.z += v.z; s.w += v.w;
        }
        partial4[(size_t)blockIdx.x * (F_IN / 4) + c4] = s;
    }
}

// ---------------------------------------------------------------------------
static inline size_t align_up(size_t v, size_t a) { return (v + a - 1) & ~(a - 1); }

extern "C" void kernel_launch(void* const* d_in, const int* in_sizes, int n_in,
                              void* d_out, int out_size, void* d_ws, size_t ws_size,
                              hipStream_t stream) {
    const float* x    = (const float*)d_in[0];
    const int*   ei   = (const int*)  d_in[1];
    const float* W    = (const float*)d_in[2];
    const float* bias = (const float*)d_in[3];

    const int n = in_sizes[0] / F_IN;     // 12000
    const int E = in_sizes[1] / 2;        // 384000
    const int G = (n + 31) >> GBITS;      // 375

    char* ws = (char*)d_ws;
    size_t off_b = 0;
    float*  dinv     = (float*)(ws + off_b); off_b = align_up(off_b + (size_t)n * 4, 256);
    float*  agg      = (float*)(ws + off_b); off_b = align_up(off_b + (size_t)F_OUT * 4, 256);

    // fast path requires n <= 32*WPR-?? (LDS bitmap) and col field <= 16 bits
    bool fast = (G <= G_MAX) && (((n + 31) >> 5) <= WPR) && (n <= 65536);

    if (fast) {
        float4* partial4 = (float4*)(ws + off_b); off_b = align_up(off_b + (size_t)G * F_IN * 4, 256);
        int* counts = (int*)(ws + off_b); off_b = align_up(off_b + (size_t)NBLK * G * 4, 256);
        int* offt   = (int*)(ws + off_b); off_b = align_up(off_b + (size_t)NBLK * G * 4, 256);
        int* base   = (int*)(ws + off_b); off_b = align_up(off_b + (size_t)G * 4, 256);
        int* endg   = (int*)(ws + off_b); off_b = align_up(off_b + (size_t)G * 4, 256);
        unsigned* bucket = (unsigned*)(ws + off_b);
        size_t need = off_b + (size_t)2 * E * 4;
        if (need <= ws_size) {
            k_count  <<<NBLK, 256, 0, stream>>>(ei, E, G, counts);
            k_prefix <<<1,    512, 0, stream>>>(counts, G, NBLK, offt, base, endg);
            k_scatter<<<NBLK, 256, 0, stream>>>(ei, E, G, offt, base, bucket);
            k_dedup_colsum<<<G, 256, 0, stream>>>(bucket, base, endg,
                                                  (const float4*)x, dinv, partial4, n);
            k_reduce_agg<<<1, 1024, 0, stream>>>(partial4, G, W, agg);
            int total4 = n * (F_OUT / 4);
            k_outer<<<(total4 + 255) / 256, 256, 0, stream>>>(dinv, agg, bias,
                                                              (float4*)d_out, n);
            return;
        }
    }

    // ---- fallback: global-bitmap path (round-4 structure) ----
    const int row_words = (int)align_up((size_t)((n + 31) / 32), 64);
    const int NB = 512;
    float4* partial4 = (float4*)(ws + off_b); off_b = align_up(off_b + (size_t)NB * F_IN * 4, 256);
    unsigned* bm = (unsigned*)(ws + off_b);
    size_t avail = (ws_size > off_b) ? (ws_size - off_b) : 0;
    long long fit = (long long)(avail / ((size_t)row_words * 4));
    int rows_per_chunk = (fit >= n) ? n : (fit > 0 ? (int)fit : 1);
    for (int r0 = 0; r0 < n; r0 += rows_per_chunk) {
        int rows = n - r0; if (rows > rows_per_chunk) rows = rows_per_chunk;
        size_t n4 = (size_t)rows * row_words / 4;
        int zgrid = (int)((n4 + 255) / 256); if (zgrid > 2048) zgrid = 2048;
        k_zero_simple<<<zgrid, 256, 0, stream>>>((float4*)bm, n4);
        k_set_bits_simple<<<(E + 255) / 256, 256, 0, stream>>>(ei, E, bm, r0, r0 + rows, row_words);
        k_degree_simple<<<(rows + 3) / 4, 256, 0, stream>>>(bm, dinv, r0, rows, row_words);
    }
    k_colsum_simple<<<NB, 256, 0, stream>>>((const float4*)x, dinv, partial4, n);
    k_reduce_agg<<<1, 1024, 0, stream>>>(partial4, NB, W, agg);
    int total4 = n * (F_OUT / 4);
    k_outer<<<(total4 + 255) / 256, 256, 0, stream>>>(dinv, agg, bias, (float4*)d_out, n);
}

// Round 8
// 46.156 us; speedup vs baseline: 2.3015x; 2.3015x over previous
//
#include <hip/hip_runtime.h>
#include <math.h>

#define F_IN  128
#define F_OUT 256
#define GBITS 5            // 32 nodes per group
#define G_MAX 380          // LDS array bound (G = ceil(n/32) = 375 for n=12000)
#define WPR   376          // padded words per LDS bitmap row (>= ceil(n/32))
#define NBLK  256          // edge-pass blocks (k_count / k_scatter / k_prefix1 must match)

// ---------------------------------------------------------------------------
// P1: per-block group histogram of incidences, written TRANSPOSED:
// counts_t[g*NBLK + b]. LDS atomics only.
// ---------------------------------------------------------------------------
__global__ __launch_bounds__(256)
void k_count(const int* __restrict__ ei, int E, int G,
             int* __restrict__ counts_t /* [G][NBLK] */) {
    __shared__ int hist[G_MAX];
    int b = blockIdx.x, t = threadIdx.x;
    for (int g = t; g < G; g += 256) hist[g] = 0;
    __syncthreads();
    int C = (E + (int)gridDim.x - 1) / (int)gridDim.x;
    int e0 = b * C, e1 = min(E, e0 + C);
    for (int e = e0 + t; e < e1; e += 256) {
        int a = ei[e], c = ei[E + e];
        atomicAdd(&hist[a >> GBITS], 1);
        atomicAdd(&hist[c >> GBITS], 1);
    }
    __syncthreads();
    for (int g = t; g < G; g += 256)
        counts_t[(size_t)g * NBLK + b] = hist[g];
}

// ---------------------------------------------------------------------------
// P2a: per-group exclusive scan over the NBLK per-block counts.
// One block per group; coalesced 256-int load; Hillis-Steele in LDS.
// off_t[g*NBLK+b] = sum_{b'<b} counts_t[g][b'];  tot[g] = group total.
// ---------------------------------------------------------------------------
__global__ __launch_bounds__(NBLK)
void k_prefix1(const int* __restrict__ counts_t, int G,
               int* __restrict__ off_t, int* __restrict__ tot) {
    __shared__ int s[NBLK];
    int g = blockIdx.x, t = threadIdx.x;
    int c = counts_t[(size_t)g * NBLK + t];
    s[t] = c;
    __syncthreads();
    #pragma unroll
    for (int d = 1; d < NBLK; d <<= 1) {
        int v = (t >= d) ? s[t - d] : 0;
        __syncthreads();
        s[t] += v;
        __syncthreads();
    }
    off_t[(size_t)g * NBLK + t] = s[t] - c;      // exclusive
    if (t == NBLK - 1) tot[g] = s[t];
}

// ---------------------------------------------------------------------------
// P2b: one block: exclusive scan of tot[G] -> base[g]; endg[g]=base+tot.
// ---------------------------------------------------------------------------
__global__ __launch_bounds__(512)
void k_prefix2(const int* __restrict__ tot, int G,
               int* __restrict__ base, int* __restrict__ endg) {
    __shared__ int s[512];
    int t = threadIdx.x;
    int c = (t < G) ? tot[t] : 0;
    s[t] = c;
    __syncthreads();
    #pragma unroll
    for (int d = 1; d < 512; d <<= 1) {
        int v = (t >= d) ? s[t - d] : 0;
        __syncthreads();
        s[t] += v;
        __syncthreads();
    }
    if (t < G) {
        base[t] = s[t] - c;
        endg[t] = s[t];
    }
}

// ---------------------------------------------------------------------------
// P3: scatter incidences into group buckets. Cursors live in LDS (fast
// atomics); bucket content per group is a deterministic multiset (order
// irrelevant downstream). pack = (node&31)<<16 | other.
// ---------------------------------------------------------------------------
__global__ __launch_bounds__(256)
void k_scatter(const int* __restrict__ ei, int E, int G,
               const int* __restrict__ off_t, const int* __restrict__ base,
               unsigned* __restrict__ bucket) {
    __shared__ int cur[G_MAX];
    int b = blockIdx.x, t = threadIdx.x;
    for (int g = t; g < G; g += 256)
        cur[g] = off_t[(size_t)g * NBLK + b] + base[g];
    __syncthreads();
    int C = (E + (int)gridDim.x - 1) / (int)gridDim.x;
    int e0 = b * C, e1 = min(E, e0 + C);
    for (int e = e0 + t; e < e1; e += 256) {
        int a = ei[e], c = ei[E + e];
        int s1 = atomicAdd(&cur[a >> GBITS], 1);
        bucket[s1] = ((unsigned)(a & 31) << 16) | (unsigned)c;
        int s2 = atomicAdd(&cur[c >> GBITS], 1);
        bucket[s2] = ((unsigned)(c & 31) << 16) | (unsigned)a;
    }
}

// ---------------------------------------------------------------------------
// P4 (fused): per group of 32 nodes — LDS bitmap dedup -> popcount -> dinv,
// then weighted colsum of those 32 x-rows -> partial. All atomics in LDS.
// ---------------------------------------------------------------------------
__global__ __launch_bounds__(256)
void k_dedup_colsum(const unsigned* __restrict__ bucket,
                    const int* __restrict__ base, const int* __restrict__ endg,
                    const float4* __restrict__ x4,
                    float* __restrict__ dinv, float4* __restrict__ partial4,
                    int n) {
    __shared__ unsigned bm[32 * WPR];     // 48128 B
    __shared__ float dloc[32];
    __shared__ float4 red[8][32];
    int g = blockIdx.x, t = threadIdx.x;

    for (int i = t; i < 32 * WPR; i += 256) bm[i] = 0;
    __syncthreads();

    int i0 = base[g], i1 = endg[g];
    for (int i = i0 + t; i < i1; i += 256) {
        unsigned w = bucket[i];
        unsigned lrow = w >> 16, col = w & 0xFFFFu;
        atomicOr(&bm[lrow * WPR + (col >> 5)], 1u << (col & 31));
    }
    __syncthreads();

    // popcount: 4 waves, 8 rows each
    int wave = t >> 6, lane = t & 63;
    int words = (n + 31) >> 5;            // 375
    for (int lrow = wave; lrow < 32; lrow += 4) {
        int node = g * 32 + lrow;
        int cnt = 0;
        for (int w = lane; w < words; w += 64)
            cnt += __popc(bm[lrow * WPR + w]);
        #pragma unroll
        for (int o = 32; o > 0; o >>= 1)
            cnt += __shfl_down(cnt, o, 64);
        if (lane == 0) {
            float dv = 1.0f / sqrtf((float)cnt);   // deg==0 -> inf, matches ref
            dloc[lrow] = dv;
            if (node < n) dinv[node] = dv;
        }
    }
    __syncthreads();

    // weighted colsum for this block's 32 rows (fixed order => deterministic)
    int c4 = t & 31, ro = t >> 5;         // ro 0..7
    float4 acc = make_float4(0.f, 0.f, 0.f, 0.f);
    for (int lrow = ro; lrow < 32; lrow += 8) {
        int node = g * 32 + lrow;
        if (node >= n) break;
        float dv = dloc[lrow];
        float4 v = x4[(size_t)node * (F_IN / 4) + c4];
        acc.x += dv * v.x; acc.y += dv * v.y;
        acc.z += dv * v.z; acc.w += dv * v.w;
    }
    red[ro][c4] = acc;
    __syncthreads();
    if (ro == 0) {
        float4 s = red[0][c4];
        #pragma unroll
        for (int k = 1; k < 8; ++k) {
            float4 v = red[k][c4];
            s.x += v.x; s.y += v.y; s.z += v.z; s.w += v.w;
        }
        partial4[(size_t)g * (F_IN / 4) + c4] = s;
    }
}

// ---------------------------------------------------------------------------
// Reduce partials -> s[128], then agg[f] = sum_k s[k]*W[k,f] (4-way k-split).
// ---------------------------------------------------------------------------
__global__ __launch_bounds__(1024)
void k_reduce_agg(const float4* __restrict__ partial4, int nparts,
                  const float* __restrict__ W, float* __restrict__ agg) {
    __shared__ float4 lds[32][32];
    __shared__ float s[F_IN];
    __shared__ float aggLds[4][F_OUT];
    int t = threadIdx.x;
    int c4 = t & 31;
    int g  = t >> 5;
    {
        float4 acc = make_float4(0.f, 0.f, 0.f, 0.f);
        for (int b = g; b < nparts; b += 32) {
            float4 v = partial4[(size_t)b * (F_IN / 4) + c4];
            acc.x += v.x; acc.y += v.y; acc.z += v.z; acc.w += v.w;
        }
        lds[g][c4] = acc;
    }
    __syncthreads();
    for (int st = 16; st > 0; st >>= 1) {
        if (g < st) {
            float4 o = lds[g + st][c4];
            float4 v = lds[g][c4];
            v.x += o.x; v.y += o.y; v.z += o.z; v.w += o.w;
            lds[g][c4] = v;
        }
        __syncthreads();
    }
    if (g == 0) {
        float4 v = lds[0][c4];
        s[c4 * 4 + 0] = v.x; s[c4 * 4 + 1] = v.y;
        s[c4 * 4 + 2] = v.z; s[c4 * 4 + 3] = v.w;
    }
    __syncthreads();
    {
        int f  = t & 255;
        int kg = t >> 8;
        float acc = 0.f;
        #pragma unroll 8
        for (int k = kg * 32; k < kg * 32 + 32; ++k)
            acc += s[k] * W[(size_t)k * F_OUT + f];
        aggLds[kg][f] = acc;
    }
    __syncthreads();
    if (t < F_OUT)
        agg[t] = aggLds[0][t] + aggLds[1][t] + aggLds[2][t] + aggLds[3][t];
}

// ---------------------------------------------------------------------------
// out[n,f] = dinv[n]*agg[f] + bias[f], float4-vectorized.
// ---------------------------------------------------------------------------
__global__ void k_outer(const float* __restrict__ dinv,
                        const float* __restrict__ agg,
                        const float* __restrict__ bias,
                        float4* __restrict__ out4, int n) {
    int i = blockIdx.x * blockDim.x + threadIdx.x;
    const int per_row = F_OUT / 4;
    int total = n * per_row;
    if (i >= total) return;
    int node = i >> 6;
    int f4   = i & 63;
    float d = dinv[node];
    float4 a  = ((const float4*)agg)[f4];
    float4 bb = ((const float4*)bias)[f4];
    float4 o;
    o.x = fmaf(d, a.x, bb.x);
    o.y = fmaf(d, a.y, bb.y);
    o.z = fmaf(d, a.z, bb.z);
    o.w = fmaf(d, a.w, bb.w);
    out4[i] = o;
}

// ---------------------------------------------------------------------------
// Fallback path (only if n too large for LDS bitmap or ws too small):
// global-bitmap zero / atomicOr / popcount (round-4 structure).
// ---------------------------------------------------------------------------
__global__ __launch_bounds__(256)
void k_zero_simple(float4* __restrict__ p, size_t n4) {
    size_t i = (size_t)blockIdx.x * blockDim.x + threadIdx.x;
    size_t stride = (size_t)gridDim.x * blockDim.x;
    float4 z = make_float4(0.f, 0.f, 0.f, 0.f);
    for (; i < n4; i += stride) p[i] = z;
}
__global__ void k_set_bits_simple(const int* __restrict__ ei, int E,
                                  unsigned* __restrict__ bm, int r0, int r1,
                                  int row_words) {
    int e = blockIdx.x * blockDim.x + threadIdx.x;
    if (e >= E) return;
    int a = ei[e];
    int b = ei[E + e];
    if (a >= r0 && a < r1)
        atomicOr(&bm[(size_t)(a - r0) * row_words + (b >> 5)], 1u << (b & 31));
    if (b >= r0 && b < r1)
        atomicOr(&bm[(size_t)(b - r0) * row_words + (a >> 5)], 1u << (a & 31));
}
__global__ __launch_bounds__(256)
void k_degree_simple(const unsigned* __restrict__ bm, float* __restrict__ dinv,
                     int r0, int rows, int row_words) {
    int wave = threadIdx.x >> 6;
    int lane = threadIdx.x & 63;
    int row  = blockIdx.x * 4 + wave;
    if (row >= rows) return;
    const unsigned* p = bm + (size_t)row * row_words;
    int cnt = 0;
    for (int w = lane; w < row_words; w += 64)
        cnt += __popc(p[w]);
    #pragma unroll
    for (int off = 32; off > 0; off >>= 1)
        cnt += __shfl_down(cnt, off, 64);
    if (lane == 0)
        dinv[r0 + row] = 1.0f / sqrtf((float)cnt);
}
__global__ __launch_bounds__(256)
void k_colsum_simple(const float4* __restrict__ x4, const float* __restrict__ dinv,
                     float4* __restrict__ partial4, int n) {
    __shared__ float4 lds[8][32];
    int t = threadIdx.x;
    int c4 = t & 31;
    int ro = t >> 5;
    int rows_per = (n + (int)gridDim.x - 1) / (int)gridDim.x;
    int rbeg = blockIdx.x * rows_per;
    int rend = rbeg + rows_per; if (rend > n) rend = n;
    float4 acc = make_float4(0.f, 0.f, 0.f, 0.f);
    for (int r = rbeg + ro; r < rend; r += 8) {
        float dv = dinv[r];
        float4 v = x4[(size_t)r * (F_IN / 4) + c4];
        acc.x += dv * v.x; acc.y += dv * v.y;
        acc.z += dv * v.z; acc.w += dv * v.w;
    }
    lds[ro][c4] = acc;
    __syncthreads();
    if (ro == 0) {
        float4 s = lds[0][c4];
        #pragma unroll
        for (int g = 1; g < 8; ++g) {
            float4 v = lds[g][c4];
            s.x += v.x; s.y += v.y; s.z += v.z; s.w += v.w;
        }
        partial4[(size_t)blockIdx.x * (F_IN / 4) + c4] = s;
    }
}

// ---------------------------------------------------------------------------
static inline size_t align_up(size_t v, size_t a) { return (v + a - 1) & ~(a - 1); }

extern "C" void kernel_launch(void* const* d_in, const int* in_sizes, int n_in,
                              void* d_out, int out_size, void* d_ws, size_t ws_size,
                              hipStream_t stream) {
    const float* x    = (const float*)d_in[0];
    const int*   ei   = (const int*)  d_in[1];
    const float* W    = (const float*)d_in[2];
    const float* bias = (const float*)d_in[3];

    const int n = in_sizes[0] / F_IN;     // 12000
    const int E = in_sizes[1] / 2;        // 384000
    const int G = (n + 31) >> GBITS;      // 375

    char* ws = (char*)d_ws;
    size_t off_b = 0;
    float*  dinv     = (float*)(ws + off_b); off_b = align_up(off_b + (size_t)n * 4, 256);
    float*  agg      = (float*)(ws + off_b); off_b = align_up(off_b + (size_t)F_OUT * 4, 256);

    // fast path requires group count within LDS bounds and node id <= 16 bits
    bool fast = (G <= G_MAX) && (((n + 31) >> 5) <= WPR) && (n <= 65536);

    if (fast) {
        float4* partial4 = (float4*)(ws + off_b); off_b = align_up(off_b + (size_t)G * F_IN * 4, 256);
        int* counts_t = (int*)(ws + off_b); off_b = align_up(off_b + (size_t)G * NBLK * 4, 256);
        int* offs_t   = (int*)(ws + off_b); off_b = align_up(off_b + (size_t)G * NBLK * 4, 256);
        int* tot    = (int*)(ws + off_b); off_b = align_up(off_b + (size_t)G * 4, 256);
        int* base   = (int*)(ws + off_b); off_b = align_up(off_b + (size_t)G * 4, 256);
        int* endg   = (int*)(ws + off_b); off_b = align_up(off_b + (size_t)G * 4, 256);
        unsigned* bucket = (unsigned*)(ws + off_b);
        size_t need = off_b + (size_t)2 * E * 4;
        if (need <= ws_size) {
            k_count  <<<NBLK, 256, 0, stream>>>(ei, E, G, counts_t);
            k_prefix1<<<G,   NBLK, 0, stream>>>(counts_t, G, offs_t, tot);
            k_prefix2<<<1,    512, 0, stream>>>(tot, G, base, endg);
            k_scatter<<<NBLK, 256, 0, stream>>>(ei, E, G, offs_t, base, bucket);
            k_dedup_colsum<<<G, 256, 0, stream>>>(bucket, base, endg,
                                                  (const float4*)x, dinv, partial4, n);
            k_reduce_agg<<<1, 1024, 0, stream>>>(partial4, G, W, agg);
            int total4 = n * (F_OUT / 4);
            k_outer<<<(total4 + 255) / 256, 256, 0, stream>>>(dinv, agg, bias,
                                                              (float4*)d_out, n);
            return;
        }
    }

    // ---- fallback: global-bitmap path (round-4 structure) ----
    const int row_words = (int)align_up((size_t)((n + 31) / 32), 64);
    const int NB = 512;
    float4* partial4 = (float4*)(ws + off_b); off_b = align_up(off_b + (size_t)NB * F_IN * 4, 256);
    unsigned* bm = (unsigned*)(ws + off_b);
    size_t avail = (ws_size > off_b) ? (ws_size - off_b) : 0;
    long long fit = (long long)(avail / ((size_t)row_words * 4));
    int rows_per_chunk = (fit >= n) ? n : (fit > 0 ? (int)fit : 1);
    for (int r0 = 0; r0 < n; r0 += rows_per_chunk) {
        int rows = n - r0; if (rows > rows_per_chunk) rows = rows_per_chunk;
        size_t n4 = (size_t)rows * row_words / 4;
        int zgrid = (int)((n4 + 255) / 256); if (zgrid > 2048) zgrid = 2048;
        k_zero_simple<<<zgrid, 256, 0, stream>>>((float4*)bm, n4);
        k_set_bits_simple<<<(E + 255) / 256, 256, 0, stream>>>(ei, E, bm, r0, r0 + rows, row_words);
        k_degree_simple<<<(rows + 3) / 4, 256, 0, stream>>>(bm, dinv, r0, rows, row_words);
    }
    k_colsum_simple<<<NB, 256, 0, stream>>>((const float4*)x, dinv, partial4, n);
    k_reduce_agg<<<1, 1024, 0, stream>>>(partial4, NB, W, agg);
    int total4 = n * (F_OUT / 4);
    k_outer<<<(total4 + 255) / 256, 256, 0, stream>>>(dinv, agg, bias, (float4*)d_out, n);
}